// Round 1
// baseline (1009.364 us; speedup 1.0000x reference)
//
#include <hip/hip_runtime.h>
#include <hip/hip_bf16.h>

#define N_ATOMS 5000
#define N_EDGES 100000
#define F 128
#define B 20
#define NL 3

constexpr float CUTOFF = 5.0f;
constexpr float PI_F = 3.14159265358979323846f;

// ---------------------------------------------------------------- init: s = emb[Z]
__global__ void init_kernel(const int* __restrict__ Z, const float* __restrict__ emb,
                            float* __restrict__ s) {
    int atom = blockIdx.x;
    int t = threadIdx.x;           // 0..127
    s[atom * F + t] = emb[Z[atom] * F + t];
}

// ---------------------------------------------------------------- phi = silu(s@W1+b1)@W2+b2
__global__ void phi_kernel(const float* __restrict__ s,
                           const float* __restrict__ w1,   // F x F
                           const float* __restrict__ b1,   // F
                           const float* __restrict__ w2,   // F x 3F
                           const float* __restrict__ b2,   // 3F
                           float* __restrict__ phi) {      // N x 3F
    __shared__ float sh_s[F];
    __shared__ float sh_h[F];
    int atom = blockIdx.x;
    int t = threadIdx.x;           // 0..127
    sh_s[t] = s[atom * F + t];
    __syncthreads();
    float acc = b1[t];
#pragma unroll 8
    for (int k = 0; k < F; ++k) acc += sh_s[k] * w1[k * F + t];
    acc = acc / (1.0f + __expf(-acc));   // silu
    sh_h[t] = acc;
    __syncthreads();
    float a0 = b2[t], a1 = b2[t + F], a2 = b2[t + 2 * F];
#pragma unroll 8
    for (int k = 0; k < F; ++k) {
        float h = sh_h[k];
        const float* row = w2 + k * 3 * F;
        a0 += h * row[t];
        a1 += h * row[t + F];
        a2 += h * row[t + 2 * F];
    }
    float* po = phi + atom * 3 * F;
    po[t] = a0; po[t + F] = a1; po[t + 2 * F] = a2;
}

// ---------------------------------------------------------------- per-edge message + scatter
// 256 threads = 2 edges x 128 feature-threads
__global__ void edge_kernel(const int* __restrict__ eidx,
                            const float* __restrict__ ediff,
                            const float* __restrict__ edist,
                            const float* __restrict__ fw,   // B x 3F
                            const float* __restrict__ fb,   // 3F
                            const float* __restrict__ phi,  // N x 3F
                            const float* __restrict__ v,    // N x 3 x F
                            float* __restrict__ ds,         // N x F
                            float* __restrict__ dv) {       // N x 3 x F
    int le = threadIdx.x >> 7;     // 0..1 (edge within block)
    int t  = threadIdx.x & 127;    // feature
    int e  = blockIdx.x * 2 + le;

    __shared__ float sh_rbf[2][B];
    __shared__ float sh_env[2];
    __shared__ float sh_unit[2][3];

    float dist = edist[e];
    if (t < B) {
        float n = (float)(t + 1);
        sh_rbf[le][t] = sinf(dist * n * (PI_F / CUTOFF)) / dist;
    }
    if (t == 0) {
        float fc = 0.5f * (cosf(PI_F * dist / CUTOFF) + 1.0f);
        sh_env[le] = (dist < CUTOFF) ? fc : 0.0f;
    }
    if (t < 3) sh_unit[le][t] = ediff[e * 3 + t] / dist;
    __syncthreads();

    int dst = eidx[e * 2 + 0];
    int src = eidx[e * 2 + 1];
    float env = sh_env[le];

    float f0 = fb[t], f1 = fb[t + F], f2 = fb[t + 2 * F];
#pragma unroll
    for (int b = 0; b < B; ++b) {
        float r = sh_rbf[le][b];
        const float* row = fw + b * 3 * F;
        f0 += r * row[t];
        f1 += r * row[t + F];
        f2 += r * row[t + 2 * F];
    }
    f0 *= env; f1 *= env; f2 *= env;

    const float* ps = phi + src * 3 * F;
    float gsv = f0 * ps[t];
    float gev = f1 * ps[t + F];
    float ms  = f2 * ps[t + 2 * F];

    atomicAdd(&ds[dst * F + t], ms);

    float ux = sh_unit[le][0], uy = sh_unit[le][1], uz = sh_unit[le][2];
    const float* vs = v + src * 3 * F;
    float* dvd = dv + dst * 3 * F;
    atomicAdd(&dvd[0 * F + t], vs[0 * F + t] * gsv + gev * ux);
    atomicAdd(&dvd[1 * F + t], vs[1 * F + t] * gsv + gev * uy);
    atomicAdd(&dvd[2 * F + t], vs[2 * F + t] * gsv + gev * uz);
}

// ---------------------------------------------------------------- per-atom update block
__global__ void update_kernel(float* __restrict__ s, float* __restrict__ v,
                              const float* __restrict__ ds, const float* __restrict__ dv,
                              const float* __restrict__ U,  // F x F
                              const float* __restrict__ V,  // F x F
                              const float* __restrict__ w1, // 2F x F
                              const float* __restrict__ b1, // F
                              const float* __restrict__ w2, // F x 3F
                              const float* __restrict__ b2) // 3F
{
    __shared__ float sh_s[F];
    __shared__ float sh_v[3 * F];
    __shared__ float sh_vn[F];
    __shared__ float sh_h[F];
    int atom = blockIdx.x;
    int t = threadIdx.x;   // 0..127

    float sn = s[atom * F + t] + ds[atom * F + t];
    sh_s[t] = sn;
#pragma unroll
    for (int d = 0; d < 3; ++d)
        sh_v[d * F + t] = v[atom * 3 * F + d * F + t] + dv[atom * 3 * F + d * F + t];
    __syncthreads();

    float uv0 = 0.f, uv1 = 0.f, uv2 = 0.f, vv0 = 0.f, vv1 = 0.f, vv2 = 0.f;
#pragma unroll 8
    for (int k = 0; k < F; ++k) {
        float uu = U[k * F + t];
        float ww = V[k * F + t];
        float x0 = sh_v[0 * F + k], x1 = sh_v[1 * F + k], x2 = sh_v[2 * F + k];
        uv0 += x0 * uu; uv1 += x1 * uu; uv2 += x2 * uu;
        vv0 += x0 * ww; vv1 += x1 * ww; vv2 += x2 * ww;
    }
    sh_vn[t] = sqrtf(vv0 * vv0 + vv1 * vv1 + vv2 * vv2);
    __syncthreads();

    float acc = b1[t];
#pragma unroll 8
    for (int k = 0; k < F; ++k) acc += sh_s[k] * w1[k * F + t];
#pragma unroll 8
    for (int k = 0; k < F; ++k) acc += sh_vn[k] * w1[(F + k) * F + t];
    acc = acc / (1.0f + __expf(-acc));   // silu
    sh_h[t] = acc;
    __syncthreads();

    float a0 = b2[t], a1 = b2[F + t], a2 = b2[2 * F + t];
#pragma unroll 8
    for (int k = 0; k < F; ++k) {
        float h = sh_h[k];
        const float* row = w2 + k * 3 * F;
        a0 += h * row[t];
        a1 += h * row[t + F];
        a2 += h * row[t + 2 * F];
    }
    // a0=avv, a1=asv, a2=ass
    float dotuv = uv0 * vv0 + uv1 * vv1 + uv2 * vv2;
    v[atom * 3 * F + 0 * F + t] = sh_v[0 * F + t] + a0 * uv0;
    v[atom * 3 * F + 1 * F + t] = sh_v[1 * F + t] + a0 * uv1;
    v[atom * 3 * F + 2 * F + t] = sh_v[2 * F + t] + a0 * uv2;
    s[atom * F + t] = sn + a1 * dotuv + a2;
}

// ---------------------------------------------------------------- readout (one wave per atom)
__global__ void readout_kernel(const float* __restrict__ s,
                               const float* __restrict__ w1,  // F x 64
                               const float* __restrict__ b1,  // 64
                               const float* __restrict__ w2,  // 64
                               const float* __restrict__ b2,  // 1
                               float* __restrict__ out) {
    __shared__ float sh_s[F];
    int atom = blockIdx.x;
    int t = threadIdx.x;   // 0..63
    sh_s[t] = s[atom * F + t];
    sh_s[t + 64] = s[atom * F + t + 64];
    __syncthreads();
    float acc = b1[t];
#pragma unroll 8
    for (int k = 0; k < F; ++k) acc += sh_s[k] * w1[k * 64 + t];
    acc = acc / (1.0f + __expf(-acc));   // silu
    float p = acc * w2[t];
#pragma unroll
    for (int off = 32; off > 0; off >>= 1) p += __shfl_down(p, off, 64);
    if (t == 0) out[atom] = p + b2[0];
}

extern "C" void kernel_launch(void* const* d_in, const int* in_sizes, int n_in,
                              void* d_out, int out_size, void* d_ws, size_t ws_size,
                              hipStream_t stream) {
    const int*   Z      = (const int*)d_in[0];
    const int*   eidx   = (const int*)d_in[1];
    const float* ediff  = (const float*)d_in[2];
    const float* edist  = (const float*)d_in[3];
    const float* emb    = (const float*)d_in[4];
    const float* msg_w1 = (const float*)d_in[5];
    const float* msg_b1 = (const float*)d_in[6];
    const float* msg_w2 = (const float*)d_in[7];
    const float* msg_b2 = (const float*)d_in[8];
    const float* filt_w = (const float*)d_in[9];
    const float* filt_b = (const float*)d_in[10];
    const float* upd_U  = (const float*)d_in[11];
    const float* upd_V  = (const float*)d_in[12];
    const float* upd_w1 = (const float*)d_in[13];
    const float* upd_b1 = (const float*)d_in[14];
    const float* upd_w2 = (const float*)d_in[15];
    const float* upd_b2 = (const float*)d_in[16];
    const float* ro_w1  = (const float*)d_in[17];
    const float* ro_b1  = (const float*)d_in[18];
    const float* ro_w2  = (const float*)d_in[19];
    const float* ro_b2  = (const float*)d_in[20];
    float* out = (float*)d_out;

    float* ws  = (float*)d_ws;
    float* s   = ws;                     // N*F
    float* v   = s + N_ATOMS * F;        // N*3*F
    float* phi = v + N_ATOMS * 3 * F;    // N*3*F
    float* ds  = phi + N_ATOMS * 3 * F;  // N*F
    float* dv  = ds + N_ATOMS * F;       // N*3*F

    init_kernel<<<N_ATOMS, F, 0, stream>>>(Z, emb, s);
    hipMemsetAsync(v, 0, (size_t)N_ATOMS * 3 * F * sizeof(float), stream);

    for (int l = 0; l < NL; ++l) {
        phi_kernel<<<N_ATOMS, F, 0, stream>>>(
            s, msg_w1 + l * F * F, msg_b1 + l * F,
            msg_w2 + l * F * 3 * F, msg_b2 + l * 3 * F, phi);
        hipMemsetAsync(ds, 0, (size_t)N_ATOMS * F * sizeof(float), stream);
        hipMemsetAsync(dv, 0, (size_t)N_ATOMS * 3 * F * sizeof(float), stream);
        edge_kernel<<<N_EDGES / 2, 256, 0, stream>>>(
            eidx, ediff, edist, filt_w + l * B * 3 * F, filt_b + l * 3 * F,
            phi, v, ds, dv);
        update_kernel<<<N_ATOMS, F, 0, stream>>>(
            s, v, ds, dv, upd_U + l * F * F, upd_V + l * F * F,
            upd_w1 + l * 2 * F * F, upd_b1 + l * F,
            upd_w2 + l * F * 3 * F, upd_b2 + l * 3 * F);
    }
    readout_kernel<<<N_ATOMS, 64, 0, stream>>>(s, ro_w1, ro_b1, ro_w2, ro_b2, out);
}

// Round 2
// 636.841 us; speedup vs baseline: 1.5850x; 1.5850x over previous
//
#include <hip/hip_runtime.h>
#include <hip/hip_bf16.h>
#include <math.h>

#define N_ATOMS 5000
#define N_EDGES 100000
#define F 128
#define B 20
#define NL 3
#define CAP 96

constexpr float CUTOFF = 5.0f;
constexpr float PI_F = 3.14159265358979323846f;

__device__ __forceinline__ float silu_f(float x) { return x / (1.0f + __expf(-x)); }

// ---------------------------------------------------------------- init: s = emb[Z]
__global__ void init_kernel(const int* __restrict__ Z, const float* __restrict__ emb,
                            float* __restrict__ s) {
    int atom = blockIdx.x;
    int t = threadIdx.x;
    s[atom * F + t] = emb[Z[atom] * F + t];
}

// ---------------------------------------------------------------- bucket edges by dst
__global__ void fill_buckets(const int* __restrict__ eidx, int* __restrict__ count,
                             int* __restrict__ bucket) {
    int e = blockIdx.x * 256 + threadIdx.x;
    if (e >= N_EDGES) return;
    int dst = eidx[2 * e];
    int pos = atomicAdd(&count[dst], 1);
    if (pos < CAP) bucket[dst * CAP + pos] = e;
}

// ---------------------------------------------------------------- phi = silu(s@W1+b1)@W2+b2, 16 atoms/block
__global__ __launch_bounds__(128) void phi_kernel(
    const float* __restrict__ s, const float* __restrict__ w1, const float* __restrict__ b1,
    const float* __restrict__ w2, const float* __restrict__ b2, float* __restrict__ phi) {
    const int TA = 16;
    __shared__ __align__(16) float sh_s[F][20];
    __shared__ __align__(16) float sh_h[F][20];
    int a0 = blockIdx.x * TA;
    int t = threadIdx.x;
#pragma unroll
    for (int a = 0; a < TA; ++a) {
        int atom = a0 + a;
        sh_s[t][a] = (atom < N_ATOMS) ? s[atom * F + t] : 0.0f;
    }
    __syncthreads();
    float acc[TA];
    float bb = b1[t];
#pragma unroll
    for (int a = 0; a < TA; ++a) acc[a] = bb;
    for (int k = 0; k < F; ++k) {
        float w = w1[k * F + t];
        const float* rp = &sh_s[k][0];
        float4 q0 = *(const float4*)(rp), q1 = *(const float4*)(rp + 4);
        float4 q2 = *(const float4*)(rp + 8), q3 = *(const float4*)(rp + 12);
        float sv[TA] = {q0.x, q0.y, q0.z, q0.w, q1.x, q1.y, q1.z, q1.w,
                        q2.x, q2.y, q2.z, q2.w, q3.x, q3.y, q3.z, q3.w};
#pragma unroll
        for (int a = 0; a < TA; ++a) acc[a] += sv[a] * w;
    }
#pragma unroll
    for (int a = 0; a < TA; ++a) sh_h[t][a] = silu_f(acc[a]);
    __syncthreads();
    float A0[TA], A1[TA], A2[TA];
    float c0 = b2[t], c1 = b2[F + t], c2 = b2[2 * F + t];
#pragma unroll
    for (int a = 0; a < TA; ++a) { A0[a] = c0; A1[a] = c1; A2[a] = c2; }
    for (int k = 0; k < F; ++k) {
        const float* wr = w2 + k * 3 * F;
        float w0 = wr[t], w1v = wr[F + t], w2v = wr[2 * F + t];
        const float* rp = &sh_h[k][0];
        float4 q0 = *(const float4*)(rp), q1 = *(const float4*)(rp + 4);
        float4 q2 = *(const float4*)(rp + 8), q3 = *(const float4*)(rp + 12);
        float hv[TA] = {q0.x, q0.y, q0.z, q0.w, q1.x, q1.y, q1.z, q1.w,
                        q2.x, q2.y, q2.z, q2.w, q3.x, q3.y, q3.z, q3.w};
#pragma unroll
        for (int a = 0; a < TA; ++a) {
            A0[a] += hv[a] * w0; A1[a] += hv[a] * w1v; A2[a] += hv[a] * w2v;
        }
    }
#pragma unroll
    for (int a = 0; a < TA; ++a) {
        int atom = a0 + a;
        if (atom < N_ATOMS) {
            float* po = phi + atom * 3 * F;
            po[t] = A0[a]; po[F + t] = A1[a]; po[2 * F + t] = A2[a];
        }
    }
}

// ---------------------------------------------------------------- per-dst edge aggregation (no atomics)
__global__ __launch_bounds__(128) void edge_agg_kernel(
    const int* __restrict__ count, const int* __restrict__ bucket,
    const int* __restrict__ eidx, const float* __restrict__ ediff,
    const float* __restrict__ edist,
    const float* __restrict__ fw, const float* __restrict__ fb,
    const float* __restrict__ phi, const float* __restrict__ v,
    float* __restrict__ ds, float* __restrict__ dv) {
    int a = blockIdx.x;
    int t = threadIdx.x;

    // filt_w column t held in registers: 60 floats
    float rfw0[B], rfw1[B], rfw2[B];
#pragma unroll
    for (int b = 0; b < B; ++b) {
        const float* row = fw + b * 3 * F;
        rfw0[b] = row[t]; rfw1[b] = row[F + t]; rfw2[b] = row[2 * F + t];
    }
    float fb0 = fb[t], fb1 = fb[F + t], fb2 = fb[2 * F + t];

    int n = count[a]; if (n > CAP) n = CAP;
    float accS = 0.f, accV0 = 0.f, accV1 = 0.f, accV2 = 0.f;

    __shared__ __align__(16) float sh_rbf[32][B];
    __shared__ float sh_env[32];
    __shared__ float sh_unit[32][3];
    __shared__ int sh_src[32];

    for (int base = 0; base < n; base += 32) {
        int cnt = min(32, n - base);
        __syncthreads();
        if (t < cnt) {
            int e = bucket[a * CAP + base + t];
            sh_src[t] = eidx[2 * e + 1];
            float d = edist[e];
            float fc = 0.5f * (cosf(PI_F * d / CUTOFF) + 1.0f);
            sh_env[t] = (d < CUTOFF) ? fc : 0.0f;
            float inv = 1.0f / d;
            sh_unit[t][0] = ediff[3 * e + 0] * inv;
            sh_unit[t][1] = ediff[3 * e + 1] * inv;
            sh_unit[t][2] = ediff[3 * e + 2] * inv;
        }
        for (int task = t; task < cnt * B; task += 128) {
            int i = task / B, b = task - i * B;
            int e = bucket[a * CAP + base + i];
            float d = edist[e];
            sh_rbf[i][b] = sinf(d * (float)(b + 1) * (PI_F / CUTOFF)) / d;
        }
        __syncthreads();
        for (int i = 0; i < cnt; ++i) {
            float f0 = fb0, f1 = fb1, f2 = fb2;
#pragma unroll
            for (int b = 0; b < B; ++b) {
                float r = sh_rbf[i][b];
                f0 += r * rfw0[b]; f1 += r * rfw1[b]; f2 += r * rfw2[b];
            }
            float env = sh_env[i];
            f0 *= env; f1 *= env; f2 *= env;
            int src = sh_src[i];
            const float* ps = phi + src * 3 * F;
            const float* vs = v + src * 3 * F;
            float gsv = f0 * ps[t];
            float gev = f1 * ps[F + t];
            float ms  = f2 * ps[2 * F + t];
            accS  += ms;
            accV0 += vs[t] * gsv         + gev * sh_unit[i][0];
            accV1 += vs[F + t] * gsv     + gev * sh_unit[i][1];
            accV2 += vs[2 * F + t] * gsv + gev * sh_unit[i][2];
        }
    }
    ds[a * F + t] = accS;
    float* dvd = dv + a * 3 * F;
    dvd[t] = accV0; dvd[F + t] = accV1; dvd[2 * F + t] = accV2;
}

// ---------------------------------------------------------------- per-atom update, 8 atoms/block
__global__ __launch_bounds__(128) void update_kernel(
    float* __restrict__ s, float* __restrict__ v,
    const float* __restrict__ ds, const float* __restrict__ dv,
    const float* __restrict__ U, const float* __restrict__ V,
    const float* __restrict__ w1, const float* __restrict__ b1,
    const float* __restrict__ w2, const float* __restrict__ b2) {
    const int TA = 8;
    __shared__ __align__(16) float sh_s[F][12];
    __shared__ __align__(16) float sh_vn[F][12];
    __shared__ __align__(16) float sh_h[F][12];
    __shared__ __align__(16) float sh_v[3][F][12];
    int a0 = blockIdx.x * TA;
    int t = threadIdx.x;
    float sn[TA];
#pragma unroll
    for (int a = 0; a < TA; ++a) {
        int atom = a0 + a;
        sn[a] = s[atom * F + t] + ds[atom * F + t];
        sh_s[t][a] = sn[a];
#pragma unroll
        for (int d = 0; d < 3; ++d)
            sh_v[d][t][a] = v[atom * 3 * F + d * F + t] + dv[atom * 3 * F + d * F + t];
    }
    __syncthreads();
    float uv[3][TA], vv[3][TA];
#pragma unroll
    for (int d = 0; d < 3; ++d)
#pragma unroll
        for (int a = 0; a < TA; ++a) { uv[d][a] = 0.f; vv[d][a] = 0.f; }
    for (int k = 0; k < F; ++k) {
        float uu = U[k * F + t], wv = V[k * F + t];
#pragma unroll
        for (int d = 0; d < 3; ++d) {
            const float* rp = &sh_v[d][k][0];
            float4 q0 = *(const float4*)(rp), q1 = *(const float4*)(rp + 4);
            float xv[TA] = {q0.x, q0.y, q0.z, q0.w, q1.x, q1.y, q1.z, q1.w};
#pragma unroll
            for (int a = 0; a < TA; ++a) { uv[d][a] += xv[a] * uu; vv[d][a] += xv[a] * wv; }
        }
    }
#pragma unroll
    for (int a = 0; a < TA; ++a)
        sh_vn[t][a] = sqrtf(vv[0][a] * vv[0][a] + vv[1][a] * vv[1][a] + vv[2][a] * vv[2][a]);
    __syncthreads();
    float h[TA];
    float bb = b1[t];
#pragma unroll
    for (int a = 0; a < TA; ++a) h[a] = bb;
    for (int k = 0; k < F; ++k) {
        float w = w1[k * F + t];
        const float* rp = &sh_s[k][0];
        float4 q0 = *(const float4*)(rp), q1 = *(const float4*)(rp + 4);
        float sv[TA] = {q0.x, q0.y, q0.z, q0.w, q1.x, q1.y, q1.z, q1.w};
#pragma unroll
        for (int a = 0; a < TA; ++a) h[a] += sv[a] * w;
    }
    for (int k = 0; k < F; ++k) {
        float w = w1[(F + k) * F + t];
        const float* rp = &sh_vn[k][0];
        float4 q0 = *(const float4*)(rp), q1 = *(const float4*)(rp + 4);
        float nv[TA] = {q0.x, q0.y, q0.z, q0.w, q1.x, q1.y, q1.z, q1.w};
#pragma unroll
        for (int a = 0; a < TA; ++a) h[a] += nv[a] * w;
    }
#pragma unroll
    for (int a = 0; a < TA; ++a) sh_h[t][a] = silu_f(h[a]);
    __syncthreads();
    float A0[TA], A1[TA], A2[TA];
    float c0 = b2[t], c1 = b2[F + t], c2 = b2[2 * F + t];
#pragma unroll
    for (int a = 0; a < TA; ++a) { A0[a] = c0; A1[a] = c1; A2[a] = c2; }
    for (int k = 0; k < F; ++k) {
        const float* wr = w2 + k * 3 * F;
        float w0 = wr[t], w1v = wr[F + t], w2v = wr[2 * F + t];
        const float* rp = &sh_h[k][0];
        float4 q0 = *(const float4*)(rp), q1 = *(const float4*)(rp + 4);
        float hv[TA] = {q0.x, q0.y, q0.z, q0.w, q1.x, q1.y, q1.z, q1.w};
#pragma unroll
        for (int a = 0; a < TA; ++a) {
            A0[a] += hv[a] * w0; A1[a] += hv[a] * w1v; A2[a] += hv[a] * w2v;
        }
    }
#pragma unroll
    for (int a = 0; a < TA; ++a) {
        int atom = a0 + a;
        float dot = uv[0][a] * vv[0][a] + uv[1][a] * vv[1][a] + uv[2][a] * vv[2][a];
#pragma unroll
        for (int d = 0; d < 3; ++d)
            v[atom * 3 * F + d * F + t] = sh_v[d][t][a] + A0[a] * uv[d][a];
        s[atom * F + t] = sn[a] + A1[a] * dot + A2[a];
    }
}

// ---------------------------------------------------------------- readout, 16 atoms/block, 64 threads
__global__ __launch_bounds__(64) void readout_kernel(
    const float* __restrict__ s, const float* __restrict__ w1, const float* __restrict__ b1,
    const float* __restrict__ w2, const float* __restrict__ b2, float* __restrict__ out) {
    const int TA = 16;
    __shared__ __align__(16) float sh_s[F][20];
    int a0 = blockIdx.x * TA;
    int t = threadIdx.x;  // 0..63
#pragma unroll
    for (int a = 0; a < TA; ++a) {
        int atom = a0 + a;
        sh_s[t][a]      = (atom < N_ATOMS) ? s[atom * F + t] : 0.0f;
        sh_s[t + 64][a] = (atom < N_ATOMS) ? s[atom * F + 64 + t] : 0.0f;
    }
    __syncthreads();
    float acc[TA];
    float bb = b1[t];
#pragma unroll
    for (int a = 0; a < TA; ++a) acc[a] = bb;
    for (int k = 0; k < F; ++k) {
        float w = w1[k * 64 + t];
        const float* rp = &sh_s[k][0];
        float4 q0 = *(const float4*)(rp), q1 = *(const float4*)(rp + 4);
        float4 q2 = *(const float4*)(rp + 8), q3 = *(const float4*)(rp + 12);
        float sv[TA] = {q0.x, q0.y, q0.z, q0.w, q1.x, q1.y, q1.z, q1.w,
                        q2.x, q2.y, q2.z, q2.w, q3.x, q3.y, q3.z, q3.w};
#pragma unroll
        for (int a = 0; a < TA; ++a) acc[a] += sv[a] * w;
    }
    float w2t = w2[t];
    float p[TA];
#pragma unroll
    for (int a = 0; a < TA; ++a) p[a] = silu_f(acc[a]) * w2t;
#pragma unroll
    for (int a = 0; a < TA; ++a)
#pragma unroll
        for (int off = 32; off > 0; off >>= 1) p[a] += __shfl_down(p[a], off, 64);
    if (t == 0) {
        float bias = b2[0];
#pragma unroll
        for (int a = 0; a < TA; ++a) {
            int atom = a0 + a;
            if (atom < N_ATOMS) out[atom] = p[a] + bias;
        }
    }
}

extern "C" void kernel_launch(void* const* d_in, const int* in_sizes, int n_in,
                              void* d_out, int out_size, void* d_ws, size_t ws_size,
                              hipStream_t stream) {
    const int*   Z      = (const int*)d_in[0];
    const int*   eidx   = (const int*)d_in[1];
    const float* ediff  = (const float*)d_in[2];
    const float* edist  = (const float*)d_in[3];
    const float* emb    = (const float*)d_in[4];
    const float* msg_w1 = (const float*)d_in[5];
    const float* msg_b1 = (const float*)d_in[6];
    const float* msg_w2 = (const float*)d_in[7];
    const float* msg_b2 = (const float*)d_in[8];
    const float* filt_w = (const float*)d_in[9];
    const float* filt_b = (const float*)d_in[10];
    const float* upd_U  = (const float*)d_in[11];
    const float* upd_V  = (const float*)d_in[12];
    const float* upd_w1 = (const float*)d_in[13];
    const float* upd_b1 = (const float*)d_in[14];
    const float* upd_w2 = (const float*)d_in[15];
    const float* upd_b2 = (const float*)d_in[16];
    const float* ro_w1  = (const float*)d_in[17];
    const float* ro_b1  = (const float*)d_in[18];
    const float* ro_w2  = (const float*)d_in[19];
    const float* ro_b2  = (const float*)d_in[20];
    float* out = (float*)d_out;

    float* ws  = (float*)d_ws;
    float* s    = ws;                     // N*F
    float* v    = s + N_ATOMS * F;        // N*3F
    float* phi  = v + N_ATOMS * 3 * F;    // N*3F
    float* ds   = phi + N_ATOMS * 3 * F;  // N*F
    float* dv   = ds + N_ATOMS * F;       // N*3F
    int* count  = (int*)(dv + N_ATOMS * 3 * F);  // N
    int* bucket = count + N_ATOMS;               // N*CAP

    init_kernel<<<N_ATOMS, F, 0, stream>>>(Z, emb, s);
    hipMemsetAsync(v, 0, (size_t)N_ATOMS * 3 * F * sizeof(float), stream);
    hipMemsetAsync(count, 0, (size_t)N_ATOMS * sizeof(int), stream);
    fill_buckets<<<(N_EDGES + 255) / 256, 256, 0, stream>>>(eidx, count, bucket);

    for (int l = 0; l < NL; ++l) {
        phi_kernel<<<(N_ATOMS + 15) / 16, 128, 0, stream>>>(
            s, msg_w1 + l * F * F, msg_b1 + l * F,
            msg_w2 + l * F * 3 * F, msg_b2 + l * 3 * F, phi);
        edge_agg_kernel<<<N_ATOMS, 128, 0, stream>>>(
            count, bucket, eidx, ediff, edist,
            filt_w + l * B * 3 * F, filt_b + l * 3 * F, phi, v, ds, dv);
        update_kernel<<<N_ATOMS / 8, 128, 0, stream>>>(
            s, v, ds, dv, upd_U + l * F * F, upd_V + l * F * F,
            upd_w1 + l * 2 * F * F, upd_b1 + l * F,
            upd_w2 + l * F * 3 * F, upd_b2 + l * 3 * F);
    }
    readout_kernel<<<(N_ATOMS + 15) / 16, 64, 0, stream>>>(s, ro_w1, ro_b1, ro_w2, ro_b2, out);
}